// Round 9
// baseline (997.847 us; speedup 1.0000x reference)
//
#include <hip/hip_runtime.h>
#include <math.h>
#include <stdint.h>

#define N_TOK 16384
#define DDIM  384
#define KCODE 8192
#define EMA   0.99f
#define EPS_F 1e-5f
#define MARGIN 0.35f
#define NB 32            // KCODE / 256 code-blocks in coarse pass

typedef _Float16 f16x8 __attribute__((ext_vector_type(8)));
typedef float    f32x4 __attribute__((ext_vector_type(4)));

#define AS1(p) ((const __attribute__((address_space(1))) uint32_t*)(p))
#define AS3(p) ((__attribute__((address_space(3))) uint32_t*)(p))

// ---- ws byte offsets (total 12,779,784 B; persistent region proven R7/R8) ----
// Region A [0, 12582912): phase1 = top2 partials (6 MB) + cb16 (6.29 MB);
//                         phase2 = embed accumulator (12.58 MB)
#define OFF_D1     0UL         // [NB][N_TOK] f32 block-best dist   (2 MB)
#define OFF_D2     2097152UL   // [NB][N_TOK] f32 block-2nd dist    (2 MB)
#define OFF_I1     4194304UL   // [NB][N_TOK] u16 block-best idx    (1 MB)
#define OFF_I2     5242880UL   // [NB][N_TOK] u16 block-2nd idx     (1 MB)
#define OFF_CB16   6291456UL   // [KCODE*DDIM] f16                  (6,291,456 B) -> 12582912
#define OFF_EMBED  0UL         // phase2: [KCODE*DDIM] f32
#define OFF_CNORM  12582912UL  // [KCODE] f32 (32 KB)   -> ends 12615680
#define OFF_FLIST  12615680UL  // [N_TOK] i32 (64 KB)   -> ends 12681216
#define OFF_FCNT   12681216UL  // i32 + pad (256 B)     -> ends 12681472
#define OFF_WSIDX  12681472UL  // [N_TOK] i32 (64 KB)   -> ends 12747008
#define OFF_COUNTS 12747008UL  // [KCODE] f32 (32 KB)   -> ends 12779776
#define OFF_SUMSQ  12779776UL  // f32
#define OFF_NACC   12779780UL  // f32

// chunk swizzle: physical 8-f16 chunk for logical chunk c in row r (proven R5)
__device__ __forceinline__ int swz(int r, int c) { return c ^ ((r >> 1) & 3); }

__device__ __forceinline__ void insert2(float x, int xi, float d[2], int id[2]) {
    if (x < d[0] || (x == d[0] && xi < id[0])) {
        d[1] = d[0]; id[1] = id[0];
        d[0] = x;    id[0] = xi;
    } else if (x < d[1] || (x == d[1] && xi < id[1])) {
        d[1] = x;    id[1] = xi;
    }
}

// one wave per code: f16 copy of codebook + row sumsq
__global__ void cvtcb_kernel(const float* __restrict__ cb, _Float16* __restrict__ cb16,
                             float* __restrict__ cnorm) {
    int code = (blockIdx.x * blockDim.x + threadIdx.x) >> 6;
    int lane = threadIdx.x & 63;
    if (code >= KCODE) return;
    const float* row = cb + (size_t)code * DDIM;
    _Float16* row16 = cb16 + (size_t)code * DDIM;
    float s = 0.f;
    #pragma unroll
    for (int r = 0; r < 6; r++) {
        float v = row[lane + 64 * r];
        s += v * v;
        row16[lane + 64 * r] = (_Float16)v;
    }
    #pragma unroll
    for (int off = 32; off > 0; off >>= 1) s += __shfl_down(s, off, 64);
    if (lane == 0) cnorm[code] = s;
}

// ---- coarse pass: f16 MFMA. 256 thr = 4 waves (wy=wv>>1 token-half, wx=wv&1
// code-half); wave 64x128; block 128 tok x 256 codes; BK=32, 12 k-iters.
// A: fp32 z -> reg (prefetched 1 iter ahead) -> cvt -> swizzled ds_write.
// B: cb16 via swizzled global_load_lds DMA. Both double-buffered, 1 barrier/iter.
// Total regs ~210/wave -> 2 waves/SIMD -> TWO independent blocks/CU (the fix).
__launch_bounds__(256)
__global__ void argmin16_kernel(const float* __restrict__ z, const _Float16* __restrict__ cb16,
                                const float* __restrict__ cnorm, char* __restrict__ wsp) {
    __shared__ _Float16 As[2 * 128 * 32];   // 16 KB dbuf (epilogue aliases)
    __shared__ _Float16 Bs[2 * 256 * 32];   // 32 KB dbuf

    const int tid  = threadIdx.x;
    const int lane = tid & 63;
    const int wv   = tid >> 6;
    const int wy   = wv >> 1;
    const int wx   = wv & 1;
    const int m0   = blockIdx.x * 128;
    const int n0   = blockIdx.y * 256;
    const int l15  = lane & 15;
    const int l4   = lane >> 4;

    f32x4 acc[4][8];
    #pragma unroll
    for (int i = 0; i < 4; i++)
        #pragma unroll
        for (int j = 0; j < 8; j++) acc[i][j] = (f32x4){0.f, 0.f, 0.f, 0.f};

    // A staging role: row = tid>>1 (0..127), half = tid&1 -> chunks {h*2, h*2+1}
    const int arow = tid >> 1, ah = tid & 1;
    const float* aglb = z + (size_t)(m0 + arow) * DDIM + ah * 16;
    const int apos0 = arow * 32 + swz(arow, ah * 2) * 8;
    const int apos1 = arow * 32 + swz(arow, ah * 2 + 1) * 8;
    // B DMA role (proven R5): issue covers 16 rows; swizzle folded into global addr
    const int brow_i = lane >> 2;
    const int bclog  = (lane & 3) ^ ((lane >> 3) & 3);
    // fragment read swizzle (proven R5)
    const int fswz = (l4 ^ ((l15 >> 1) & 3)) * 8;

    // ---- prologue: stage kc=0 into buf0; prefetch A regs for kc=32 ----
    float4 ar[4];
    #pragma unroll
    for (int q = 0; q < 4; q++) ar[q] = *(const float4*)(aglb + q * 4);
    #pragma unroll
    for (int r = 0; r < 4; r++) {
        int issue = wv * 4 + r;
        int row   = issue * 16 + brow_i;
        const _Float16* gp = cb16 + (size_t)(n0 + row) * DDIM + bclog * 8;
        __builtin_amdgcn_global_load_lds(AS1(gp), AS3(Bs + issue * 512), 16, 0, 0);
    }
    {
        f16x8 h0, h1;
        h0[0]=(_Float16)ar[0].x; h0[1]=(_Float16)ar[0].y; h0[2]=(_Float16)ar[0].z; h0[3]=(_Float16)ar[0].w;
        h0[4]=(_Float16)ar[1].x; h0[5]=(_Float16)ar[1].y; h0[6]=(_Float16)ar[1].z; h0[7]=(_Float16)ar[1].w;
        h1[0]=(_Float16)ar[2].x; h1[1]=(_Float16)ar[2].y; h1[2]=(_Float16)ar[2].z; h1[3]=(_Float16)ar[2].w;
        h1[4]=(_Float16)ar[3].x; h1[5]=(_Float16)ar[3].y; h1[6]=(_Float16)ar[3].z; h1[7]=(_Float16)ar[3].w;
        *(f16x8*)(As + apos0) = h0;
        *(f16x8*)(As + apos1) = h1;
    }
    #pragma unroll
    for (int q = 0; q < 4; q++) ar[q] = *(const float4*)(aglb + 32 + q * 4);
    __syncthreads();

    for (int kc = 0; kc < DDIM; kc += 32) {
        const int cur = (kc >> 5) & 1;
        const _Float16* asc = As + cur * (128 * 32);
        const _Float16* bsc = Bs + cur * (256 * 32);

        // frags from current buffers (ready per previous barrier)
        f16x8 af[4], bf[8];
        #pragma unroll
        for (int im = 0; im < 4; im++)
            af[im] = *(const f16x8*)(asc + (wy * 64 + im * 16 + l15) * 32 + fswz);
        #pragma unroll
        for (int in = 0; in < 8; in++)
            bf[in] = *(const f16x8*)(bsc + (wx * 128 + in * 16 + l15) * 32 + fswz);

        // stage next tile into other buffers
        if (kc + 32 < DDIM) {
            _Float16* asn = As + (cur ^ 1) * (128 * 32);
            _Float16* bsn = Bs + (cur ^ 1) * (256 * 32);
            #pragma unroll
            for (int r = 0; r < 4; r++) {
                int issue = wv * 4 + r;
                int row   = issue * 16 + brow_i;
                const _Float16* gp = cb16 + (size_t)(n0 + row) * DDIM + (kc + 32) + bclog * 8;
                __builtin_amdgcn_global_load_lds(AS1(gp), AS3(bsn + issue * 512), 16, 0, 0);
            }
            f16x8 h0, h1;
            h0[0]=(_Float16)ar[0].x; h0[1]=(_Float16)ar[0].y; h0[2]=(_Float16)ar[0].z; h0[3]=(_Float16)ar[0].w;
            h0[4]=(_Float16)ar[1].x; h0[5]=(_Float16)ar[1].y; h0[6]=(_Float16)ar[1].z; h0[7]=(_Float16)ar[1].w;
            h1[0]=(_Float16)ar[2].x; h1[1]=(_Float16)ar[2].y; h1[2]=(_Float16)ar[2].z; h1[3]=(_Float16)ar[2].w;
            h1[4]=(_Float16)ar[3].x; h1[5]=(_Float16)ar[3].y; h1[6]=(_Float16)ar[3].z; h1[7]=(_Float16)ar[3].w;
            *(f16x8*)(asn + apos0) = h0;
            *(f16x8*)(asn + apos1) = h1;
            if (kc + 64 < DDIM) {
                #pragma unroll
                for (int q = 0; q < 4; q++) ar[q] = *(const float4*)(aglb + kc + 64 + q * 4);
            }
        }

        #pragma unroll
        for (int im = 0; im < 4; im++)
            #pragma unroll
            for (int in = 0; in < 8; in++)
                acc[im][in] = __builtin_amdgcn_mfma_f32_16x16x32_f16(af[im], bf[in], acc[im][in], 0, 0, 0);

        __syncthreads();
    }

    // epilogue arrays alias As (all reads of As complete after final barrier)
    float* xd1 = (float*)As;           // [128*2]
    float* xd2 = xd1 + 256;
    int*   xi1 = (int*)(xd1 + 512);
    int*   xi2 = (int*)(xd1 + 768);

    // dist = ||c||^2 - 2 z.c ; C/D: col(code)=l15, row(token)=l4*4+reg [proven R4]
    float cn[8]; int cid[8];
    #pragma unroll
    for (int in = 0; in < 8; in++) {
        cid[in] = n0 + wx * 128 + in * 16 + l15;
        cn[in] = cnorm[cid[in]];
    }
    #pragma unroll
    for (int im = 0; im < 4; im++) {
        #pragma unroll
        for (int reg = 0; reg < 4; reg++) {
            float d[2] = {3.4e38f, 3.4e38f};
            int  id[2] = {0, 0};
            #pragma unroll
            for (int in = 0; in < 8; in++)
                insert2(cn[in] - 2.f * acc[im][in][reg], cid[in], d, id);
            #pragma unroll
            for (int off = 1; off < 16; off <<= 1) {
                float od0 = __shfl_xor(d[0], off, 16);
                int   oi0 = __shfl_xor(id[0], off, 16);
                float od1 = __shfl_xor(d[1], off, 16);
                int   oi1 = __shfl_xor(id[1], off, 16);
                insert2(od0, oi0, d, id);
                insert2(od1, oi1, d, id);
            }
            if (l15 == 0) {
                int tl = wy * 64 + im * 16 + l4 * 4 + reg;
                xd1[tl * 2 + wx] = d[0]; xi1[tl * 2 + wx] = id[0];
                xd2[tl * 2 + wx] = d[1]; xi2[tl * 2 + wx] = id[1];
            }
        }
    }
    __syncthreads();
    if (tid < 128) {
        float d[2] = {3.4e38f, 3.4e38f};
        int  id[2] = {0, 0};
        #pragma unroll
        for (int x = 0; x < 2; x++) {
            insert2(xd1[tid * 2 + x], xi1[tid * 2 + x], d, id);
            insert2(xd2[tid * 2 + x], xi2[tid * 2 + x], d, id);
        }
        size_t o = (size_t)blockIdx.y * N_TOK + m0 + tid;
        ((float*)(wsp + OFF_D1))[o] = d[0];
        ((float*)(wsp + OFF_D2))[o] = d[1];
        ((uint16_t*)(wsp + OFF_I1))[o] = (uint16_t)id[0];
        ((uint16_t*)(wsp + OFF_I2))[o] = (uint16_t)id[1];
    }
}

// merge NB block-top2 entries -> global top-2; flag near-ties
__global__ void topmerge_kernel(const char* __restrict__ wsp,
                                int* __restrict__ ws_idx, float* __restrict__ out_idx,
                                int* __restrict__ fcnt, int* __restrict__ flist) {
    int t = blockIdx.x * blockDim.x + threadIdx.x;
    if (t >= N_TOK) return;
    const float*    pd1 = (const float*)(wsp + OFF_D1);
    const float*    pd2 = (const float*)(wsp + OFF_D2);
    const uint16_t* pi1 = (const uint16_t*)(wsp + OFF_I1);
    const uint16_t* pi2 = (const uint16_t*)(wsp + OFF_I2);
    float d[2] = {3.4e38f, 3.4e38f};
    int  id[2] = {0, 0};
    for (int nb = 0; nb < NB; nb++) {
        size_t o = (size_t)nb * N_TOK + t;
        insert2(pd1[o], (int)pi1[o], d, id);
        insert2(pd2[o], (int)pi2[o], d, id);
    }
    ws_idx[t] = id[0];
    out_idx[t] = (float)id[0];
    if (d[1] - d[0] < MARGIN) {
        int s = atomicAdd(fcnt, 1);
        flist[s] = t;
    }
}

// exact fp32 rescore: one wave per flagged token; candidates = 64 block-top2
// entries (lane = nb*2+rk) within the margin window (machinery proven R7)
__launch_bounds__(256)
__global__ void rescore_kernel(const float* __restrict__ z, const float* __restrict__ cb,
                               const float* __restrict__ cnorm, const char* __restrict__ wsp,
                               const int* __restrict__ flist, const int* __restrict__ fcnt,
                               int* __restrict__ ws_idx, float* __restrict__ out_idx) {
    const int lane = threadIdx.x & 63;
    const int wv   = threadIdx.x >> 6;
    const int count = fcnt[0];
    const int nb = lane >> 1, rk = lane & 1;

    for (int s = blockIdx.x * 4 + wv; s < count; s += gridDim.x * 4) {
        int tok = flist[s];
        float zv[6];
        #pragma unroll
        for (int r = 0; r < 6; r++) zv[r] = z[(size_t)tok * DDIM + lane + 64 * r];
        size_t o = (size_t)nb * N_TOK + tok;
        float ed; int ei;
        if (rk == 0) {
            ed = ((const float*)(wsp + OFF_D1))[o];
            ei = (int)((const uint16_t*)(wsp + OFF_I1))[o];
        } else {
            ed = ((const float*)(wsp + OFF_D2))[o];
            ei = (int)((const uint16_t*)(wsp + OFF_I2))[o];
        }
        float dmin = ed;
        #pragma unroll
        for (int off = 32; off > 0; off >>= 1) dmin = fminf(dmin, __shfl_xor(dmin, off, 64));
        unsigned long long mask = __ballot(ed < dmin + MARGIN);
        float bd = 3.4e38f; int bi = 0x7fffffff;
        while (mask) {
            int src = __ffsll((long long)mask) - 1;
            mask &= mask - 1;
            int c = __shfl(ei, src, 64);
            const float* cr = cb + (size_t)c * DDIM;
            float acc = 0.f;
            #pragma unroll
            for (int r = 0; r < 6; r++) acc = fmaf(zv[r], cr[lane + 64 * r], acc);
            #pragma unroll
            for (int off = 32; off > 0; off >>= 1) acc += __shfl_xor(acc, off, 64);
            float dist = cnorm[c] - 2.f * acc;
            if (dist < bd || (dist == bd && c < bi)) { bd = dist; bi = c; }
        }
        if (lane == 0) {
            ws_idx[tok] = bi;
            out_idx[tok] = (float)bi;
        }
    }
}

__global__ void gather_scatter_kernel(const float* __restrict__ z, const float* __restrict__ cb,
                                      const int* __restrict__ ws_idx,
                                      float* __restrict__ out_q, float* __restrict__ embed_ws,
                                      float* __restrict__ counts, float* __restrict__ sumsq) {
    int t = (blockIdx.x * blockDim.x + threadIdx.x) >> 6;
    int lane = threadIdx.x & 63;
    if (t >= N_TOK) return;
    int k = ws_idx[t];
    const float* zr = z + (size_t)t * DDIM;
    const float* cr = cb + (size_t)k * DDIM;
    float* qr = out_q + (size_t)t * DDIM;
    float* er = embed_ws + (size_t)k * DDIM;
    float s = 0.f;
    #pragma unroll
    for (int r = 0; r < 6; r++) {
        int d = lane + 64 * r;
        float zv = zr[d];
        float qv = cr[d];
        qr[d] = qv;
        float df = zv - qv;
        s += df * df;
        atomicAdd(er + d, zv);
    }
    #pragma unroll
    for (int off = 32; off > 0; off >>= 1) s += __shfl_down(s, off, 64);
    if (lane == 0) {
        atomicAdd(sumsq, s);
        atomicAdd(counts + k, 1.0f);
    }
}

__global__ void cluster_kernel(const float* __restrict__ ema_cs, const float* __restrict__ counts,
                               float* __restrict__ out_ncs, float* __restrict__ n_acc,
                               const float* __restrict__ sumsq, float* __restrict__ out_loss) {
    int i = blockIdx.x * blockDim.x + threadIdx.x;
    float v = 0.f;
    if (i < KCODE) {
        v = EMA * ema_cs[i] + (1.f - EMA) * counts[i];
        out_ncs[i] = v;
    }
    __shared__ float sm[4];
    int lane = threadIdx.x & 63, w = threadIdx.x >> 6;
    #pragma unroll
    for (int off = 32; off > 0; off >>= 1) v += __shfl_down(v, off, 64);
    if (lane == 0) sm[w] = v;
    __syncthreads();
    if (threadIdx.x == 0) {
        atomicAdd(n_acc, sm[0] + sm[1] + sm[2] + sm[3]);
        if (blockIdx.x == 0) {
            out_loss[0] = 1.25f * sumsq[0] / (float)(N_TOK * DDIM);
        }
    }
}

__global__ void codebook_kernel(const float* __restrict__ ema_es, const float* __restrict__ embed_ws,
                                const float* __restrict__ ncs, const float* __restrict__ n_acc,
                                float* __restrict__ out_es, float* __restrict__ out_cb) {
    int i = blockIdx.x * blockDim.x + threadIdx.x;
    if (i >= KCODE * DDIM) return;
    float es = EMA * ema_es[i] + (1.f - EMA) * embed_ws[i];
    out_es[i] = es;
    int k = i / DDIM;
    float n = n_acc[0];
    float smooth = (ncs[k] + EPS_F) / (n + (float)KCODE * EPS_F) * n;
    out_cb[i] = es / smooth;
}

extern "C" void kernel_launch(void* const* d_in, const int* in_sizes, int n_in,
                              void* d_out, int out_size, void* d_ws, size_t ws_size,
                              hipStream_t stream) {
    const float* z       = (const float*)d_in[0];
    const float* cb      = (const float*)d_in[1];
    const float* ema_cs  = (const float*)d_in[2];
    const float* ema_es  = (const float*)d_in[3];

    float* out      = (float*)d_out;
    float* out_q    = out;
    float* out_idx  = out + 6291456;
    float* out_loss = out + 6307840;
    float* out_ncs  = out + 6307841;
    float* out_es   = out + 6316033;
    float* out_cb   = out + 9461761;

    char* w = (char*)d_ws;
    _Float16*  cb16   = (_Float16*) (w + OFF_CB16);
    float*     cnorm  = (float*)    (w + OFF_CNORM);
    int*       flist  = (int*)      (w + OFF_FLIST);
    int*       fcnt   = (int*)      (w + OFF_FCNT);
    float*     embed  = (float*)    (w + OFF_EMBED);
    int*       ws_idx = (int*)      (w + OFF_WSIDX);
    float*     counts = (float*)    (w + OFF_COUNTS);
    float*     sumsq  = (float*)    (w + OFF_SUMSQ);
    float*     n_acc  = (float*)    (w + OFF_NACC);

    hipMemsetAsync(w + OFF_FCNT, 0, 256, stream);
    hipMemsetAsync(w + OFF_COUNTS, 0, 32768 + 8, stream);    // counts + sumsq + n_acc

    cvtcb_kernel<<<KCODE / 4, 256, 0, stream>>>(cb, cb16, cnorm);

    dim3 grid_am(N_TOK / 128, KCODE / 256, 1);
    argmin16_kernel<<<grid_am, 256, 0, stream>>>(z, cb16, cnorm, w);

    topmerge_kernel<<<N_TOK / 256, 256, 0, stream>>>(w, ws_idx, out_idx, fcnt, flist);

    rescore_kernel<<<256, 256, 0, stream>>>(z, cb, cnorm, w, flist, fcnt, ws_idx, out_idx);

    // phase1 scratch dead; reuse region A as embed-sum accumulator
    hipMemsetAsync(w + OFF_EMBED, 0, (size_t)KCODE * DDIM * sizeof(float), stream);

    gather_scatter_kernel<<<N_TOK * 64 / 256, 256, 0, stream>>>(z, cb, ws_idx, out_q, embed, counts, sumsq);
    cluster_kernel<<<(KCODE + 255) / 256, 256, 0, stream>>>(ema_cs, counts, out_ncs, n_acc, sumsq, out_loss);
    codebook_kernel<<<(KCODE * DDIM) / 256, 256, 0, stream>>>(ema_es, embed, out_ncs, n_acc, out_es, out_cb);
}